// Round 16
// baseline (2179.817 us; speedup 1.0000x reference)
//
#include <hip/hip_runtime.h>
#include <hip/hip_bf16.h>

#define B_   64
#define S_   800
#define DIN_ 64
#define D_   512
#define H_   8
#define DH_  64
#define M_   64
#define L_   2
#define FF_  2048

typedef __hip_bfloat16 bf16;
typedef __attribute__((ext_vector_type(8))) short bf16x8;
typedef __attribute__((ext_vector_type(4))) float f32x4;
typedef __attribute__((ext_vector_type(2))) float f32x2;

#define NORM_ 0.35355339059327373f   // 64^(-1/4)

__device__ __forceinline__ float bf2f(unsigned short s){
  return __uint_as_float(((unsigned)s)<<16);
}
// tanh-approx GELU with hardware exp: tanh(u) = 1 - 2/(1+e^{2u}).
__device__ __forceinline__ float gelu_f(float x){
  float u = 0.7978845608028654f*(x + 0.044715f*x*x*x);
  float e = __expf(2.f*u);
  float t = 1.f - 2.f/(1.f + e);
  return 0.5f*x*(1.f + t);
}
__device__ __forceinline__ void st_bf4(bf16* p, float4 v){
  union { bf16 b[4]; unsigned long long u; } q;
  q.b[0]=__float2bfloat16(v.x); q.b[1]=__float2bfloat16(v.y);
  q.b[2]=__float2bfloat16(v.z); q.b[3]=__float2bfloat16(v.w);
  *(unsigned long long*)p = q.u;
}
__device__ __forceinline__ void gld16(const void* g, void* l){
  __builtin_amdgcn_global_load_lds((const __attribute__((address_space(1))) void*)g,
                                   (__attribute__((address_space(3))) void*)l, 16, 0, 0);
}

// XCD-chunked bijective block swizzle (m204)
__device__ __forceinline__ void swz_xy(int gx, int& bx, int& by){
  const int nwg = (int)gridDim.x, orig = (int)blockIdx.x;
  const int q = nwg>>3, r = nwg&7;
  const int xcd = orig&7, lin = orig>>3;
  const int wg = (xcd<r ? xcd*(q+1) : r*(q+1)+(xcd-r)*q) + lin;
  bx = wg % gx;  by = wg / gx;
}

// ================= 256x256 / BK=64 tile core (dbuf, known-good) ============
__device__ __forceinline__ void gemm_tile256(const bf16* __restrict__ A,
                                             const bf16* __restrict__ Wt,
                                             int rows, int K, int bx, int by,
                                             f32x4 (&acc)[8][4])
{
  __shared__ bf16 As[2][16384];
  __shared__ bf16 Bs[2][16384];
  const int tid = threadIdx.x, wave = tid>>6, lane = tid&63;
  const int wr = wave>>2, wc = wave&3;
  const int lr = lane&15, hi = lane>>4;
  const int row0 = by*256, col0 = bx*256;
  const int srow = tid>>3;
  const int scol = ((tid&7) ^ ((srow>>1)&7))*8;  // pre-swizzled source chunk
  const int keyq = (lr>>1)&7;                    // read-side XOR key
  const bf16* gA[4]; const bf16* gB[4];
  #pragma unroll
  for (int i=0;i<4;i++){
    const int ra = min(row0 + i*64 + srow, rows-1);
    gA[i] = A  + (size_t)ra*K + scol;
    gB[i] = Wt + (size_t)(col0 + i*64 + srow)*K + scol;
  }
  const int dbase = wave*512;
  const int NT = K>>6;
  #pragma unroll
  for (int i=0;i<4;i++){
    gld16(gA[i], &As[0][i*4096 + dbase]);
    gld16(gB[i], &Bs[0][i*4096 + dbase]);
  }
  __syncthreads();
  for (int t=0; t<NT; ++t){
    const int p = t&1;
    if (t+1 < NT){
      const int k0 = (t+1)<<6;
      #pragma unroll
      for (int i=0;i<4;i++){
        gld16(gA[i] + k0, &As[p^1][i*4096 + dbase]);
        gld16(gB[i] + k0, &Bs[p^1][i*4096 + dbase]);
      }
    }
    #pragma unroll
    for (int ks=0; ks<2; ++ks){
      const int co = ((ks*4 + hi) ^ keyq)*8;
      bf16x8 af[8], bv[4];
      #pragma unroll
      for (int mi=0;mi<8;mi++)
        af[mi] = *(const bf16x8*)&As[p][(wr*128 + mi*16 + lr)*64 + co];
      #pragma unroll
      for (int ni=0;ni<4;ni++)
        bv[ni] = *(const bf16x8*)&Bs[p][(wc*64 + ni*16 + lr)*64 + co];
      #pragma unroll
      for (int mi=0;mi<8;mi++)
        #pragma unroll
        for (int ni=0;ni<4;ni++)
          acc[mi][ni] = __builtin_amdgcn_mfma_f32_16x16x32_bf16(af[mi], bv[ni], acc[mi][ni], 0,0,0);
    }
    __syncthreads();
  }
}

// ---------------- standard 256-tile GEMM (res/out bf16) --------------------
template<int ACT, int RES, int OUTB>
__global__ __launch_bounds__(512,2)
void gemm256_k(const bf16* __restrict__ A, const bf16* __restrict__ Wt,
               const float* __restrict__ bias, const bf16* __restrict__ res,
               float* __restrict__ Cf, bf16* __restrict__ Cb,
               int rows, int N, int K, int gx)
{
  int bx, by;  swz_xy(gx, bx, by);
  f32x4 acc[8][4];
  #pragma unroll
  for (int i=0;i<8;i++)
    #pragma unroll
    for (int j=0;j<4;j++) acc[i][j] = (f32x4){0.f,0.f,0.f,0.f};
  gemm_tile256(A, Wt, rows, K, bx, by, acc);
  const int tid=threadIdx.x, wave=tid>>6, lane=tid&63;
  const int wr=wave>>2, wc=wave&3, lr=lane&15, hi=lane>>4;
  const int row0=by*256, col0=bx*256;
  #pragma unroll
  for (int mi=0;mi<8;mi++){
    #pragma unroll
    for (int i=0;i<4;i++){
      const int r = row0 + wr*128 + mi*16 + hi*4 + i;
      if (r >= rows) continue;
      #pragma unroll
      for (int ni=0;ni<4;ni++){
        const int c = col0 + wc*64 + ni*16 + lr;
        float v = acc[mi][ni][i] + bias[c];
        if (ACT) v = gelu_f(v);
        if (RES) v += bf2f(*(const unsigned short*)&res[(size_t)r*N + c]);
        if (OUTB) Cb[(size_t)r*N + c] = __float2bfloat16(v);
        else      Cf[(size_t)r*N + c] = v;
      }
    }
  }
}

// ---------------- mega 256-tile GEMM: N=1536 [ddq|ddk|v] -------------------
// Stabilizer-free; diag reconstructed from dd via invm2 (proj = D·Q^T).
__global__ __launch_bounds__(512,1)
void mega256_k(const bf16* __restrict__ A, const bf16* __restrict__ Wcat,
               const float* __restrict__ bcat, const float* __restrict__ invm2,
               int rows,
               bf16* __restrict__ qpb, bf16* __restrict__ ddk,
               bf16* __restrict__ vbf, int gx)
{
  int bx, by;  swz_xy(gx, bx, by);
  f32x4 acc[8][4];
  #pragma unroll
  for (int i=0;i<8;i++)
    #pragma unroll
    for (int j=0;j<4;j++) acc[i][j] = (f32x4){0.f,0.f,0.f,0.f};
  gemm_tile256(A, Wcat, rows, 512, bx, by, acc);
  const int tid=threadIdx.x, wave=tid>>6, lane=tid&63;
  const int wr=wave>>2, wc=wave&3, lr=lane&15, hi=lane>>4;
  const int row0 = by*256;
  const int cbase = bx*256 + wc*64;
  float bb[4];
  #pragma unroll
  for (int ni=0;ni<4;ni++) bb[ni] = bcat[cbase + ni*16 + lr];

  if (bx < 4){                       // dd sections
    const int isK = bx>>1;
    const int h = (bx&1)*4 + wc;
    float im[4];
    #pragma unroll
    for (int ni=0;ni<4;ni++) im[ni] = invm2[ni*16 + lr];
    float ds[32];
    #pragma unroll
    for (int mi=0;mi<8;mi++)
      #pragma unroll
      for (int i=0;i<4;i++){
        float v0=acc[mi][0][i]+bb[0], v1=acc[mi][1][i]+bb[1];
        float v2=acc[mi][2][i]+bb[2], v3=acc[mi][3][i]+bb[3];
        ds[mi*4+i] = v0*v0*im[0] + v1*v1*im[1] + v2*v2*im[2] + v3*v3*im[3];
      }
    #pragma unroll
    for (int st=1; st<=8; st<<=1)
      #pragma unroll
      for (int idx=0;idx<32;idx++) ds[idx] += __shfl_xor(ds[idx], st);
    #pragma unroll
    for (int mi=0;mi<8;mi++){
      #pragma unroll
      for (int i=0;i<4;i++){
        const int r = row0 + wr*128 + mi*16 + hi*4 + i;
        if (r >= rows) continue;
        const float dg = 0.5f*ds[mi*4+i];
        if (!isK){
          #pragma unroll
          for (int ni=0;ni<4;ni++)
            qpb[(size_t)r*512 + h*64 + ni*16 + lr] =
                __float2bfloat16(0.125f*(__expf(acc[mi][ni][i]+bb[ni] - dg) + 1e-4f));
        } else {
          #pragma unroll
          for (int ni=0;ni<4;ni++)
            ddk[(size_t)r*512 + h*64 + ni*16 + lr] =
                __float2bfloat16(acc[mi][ni][i]+bb[ni] - dg);
        }
      }
    }
  } else {                           // v section
    const int colb = (bx-4)*256 + wc*64;
    #pragma unroll
    for (int mi=0;mi<8;mi++){
      #pragma unroll
      for (int i=0;i<4;i++){
        const int r = row0 + wr*128 + mi*16 + hi*4 + i;
        if (r >= rows) continue;
        #pragma unroll
        for (int ni=0;ni<4;ni++)
          vbf[(size_t)r*512 + colb + ni*16 + lr] =
              __float2bfloat16(acc[mi][ni][i] + bb[ni]);
      }
    }
  }
}

// ================= old 128x128 core (embed only, K=64) =====================
__device__ __forceinline__ void gemm_tile(const bf16* __restrict__ A,
                                          const bf16* __restrict__ Wt,
                                          int rows, int K, int bx, int by,
                                          f32x4 (&acc)[4][4])
{
  __shared__ bf16 As[3*4096];
  __shared__ bf16 Bs[3*4096];
  const int tid = threadIdx.x, wave = tid>>6, lane = tid&63;
  const int row0 = by*128, col0 = bx*128;
  const int wm = (wave>>1)*64, wn = (wave&1)*64;
  const int lr = lane&15;
  const int lk = ((lane>>4) ^ ((lane>>1)&3))*8;
  const int c0 = wave*2, c1 = c0+1;
  const int sub = lane>>2;
  const int kq = (((lane&3) ^ ((lane>>3)&3)))*8;
  const int ra0 = min(row0 + c0*16 + sub, rows-1);
  const int ra1 = min(row0 + c1*16 + sub, rows-1);
  const bf16* gA0 = A + (size_t)ra0*K + kq;
  const bf16* gA1 = A + (size_t)ra1*K + kq;
  const bf16* gB0 = Wt + (size_t)(col0 + c0*16 + sub)*K + kq;
  const bf16* gB1 = Wt + (size_t)(col0 + c1*16 + sub)*K + kq;
  const int o0 = c0*512, o1 = c1*512;
  const int nt = K>>5;
  gld16(gA0, &As[o0]);  gld16(gA1, &As[o1]);
  gld16(gB0, &Bs[o0]);  gld16(gB1, &Bs[o1]);
  __syncthreads();
  int cur = 0;
  for (int t=0; t<nt; ++t){
    const int nxt = (cur+4096 > 8192) ? 0 : cur+4096;
    if (t+1 < nt){
      const int k0 = (t+1)*32;
      gld16(gA0+k0, &As[nxt+o0]);  gld16(gA1+k0, &As[nxt+o1]);
      gld16(gB0+k0, &Bs[nxt+o0]);  gld16(gB1+k0, &Bs[nxt+o1]);
    }
    bf16x8 af[4], bv[4];
    #pragma unroll
    for (int mi=0;mi<4;mi++) af[mi] = *(const bf16x8*)&As[cur + (wm+mi*16+lr)*32 + lk];
    #pragma unroll
    for (int ni=0;ni<4;ni++) bv[ni] = *(const bf16x8*)&Bs[cur + (wn+ni*16+lr)*32 + lk];
    #pragma unroll
    for (int mi=0;mi<4;mi++)
      #pragma unroll
      for (int ni=0;ni<4;ni++)
        acc[mi][ni] = __builtin_amdgcn_mfma_f32_16x16x32_bf16(af[mi], bv[ni], acc[mi][ni], 0,0,0);
    __syncthreads();
    cur = nxt;
  }
}

template<int ACT, int RES, int OUTB>
__global__ __launch_bounds__(256)
void gemm2_k(const bf16* __restrict__ A, const bf16* __restrict__ Wt,
             const float* __restrict__ bias, const bf16* __restrict__ res,
             float* __restrict__ Cf, bf16* __restrict__ Cb,
             int rows, int N, int K, int res_mod, int gx)
{
  int bx, by;  swz_xy(gx, bx, by);
  f32x4 acc[4][4];
  #pragma unroll
  for (int i=0;i<4;i++)
    #pragma unroll
    for (int j=0;j<4;j++) acc[i][j] = (f32x4){0.f,0.f,0.f,0.f};
  gemm_tile(A, Wt, rows, K, bx, by, acc);
  const int tid=threadIdx.x, wave=tid>>6, lane=tid&63;
  const int wm=(wave>>1)*64, wn=(wave&1)*64, lr=lane&15, hi=lane>>4;
  const int row0=by*128, col0=bx*128;
  #pragma unroll
  for (int mi=0;mi<4;mi++){
    #pragma unroll
    for (int i=0;i<4;i++){
      const int r = row0 + wm + mi*16 + hi*4 + i;
      if (r >= rows) continue;
      #pragma unroll
      for (int ni=0;ni<4;ni++){
        const int c = col0 + wn + ni*16 + lr;
        float v = acc[mi][ni][i] + bias[c];
        if (ACT) v = gelu_f(v);
        if (RES) v += bf2f(*(const unsigned short*)&res[(size_t)(res_mod ? (r % res_mod) : r)*N + c]);
        if (OUTB) Cb[(size_t)r*N + c] = __float2bfloat16(v);
        else      Cf[(size_t)r*N + c] = v;
      }
    }
  }
}

// ------- weight transpose+convert with column remap ------------------------
__global__ __launch_bounds__(256)
void convT_k(const float* __restrict__ src, bf16* __restrict__ dst, int K, int N,
             int mapbase, int mapstride)
{
  __shared__ float t[32][33];
  const int n0 = blockIdx.x*32, k0 = blockIdx.y*32;
  const int j = threadIdx.x&31, i0 = threadIdx.x>>5;
  #pragma unroll
  for (int i=i0; i<32; i+=8) t[i][j] = src[(size_t)(k0+i)*N + n0 + j];
  __syncthreads();
  #pragma unroll
  for (int i=i0; i<32; i+=8){
    const int n = n0 + i;
    const int rn = mapbase + (n>>6)*mapstride + (n&63);
    dst[(size_t)rn*K + k0 + j] = __float2bfloat16(t[j][i]);
  }
}

__global__ void conv_k(const float* __restrict__ src, bf16* __restrict__ dst, int n4)
{
  int i = blockIdx.x*256 + threadIdx.x;
  if (i < n4){ float4 v = ((const float4*)src)[i]; st_bf4(dst + (size_t)i*4, v); }
}

// folded feature weight into Wcat: out row = mapbase + h*64 + m
__global__ __launch_bounds__(256)
void projw_k(const float* __restrict__ w, const float* __restrict__ proj,
             bf16* __restrict__ Wcat, int mapbase)
{
  __shared__ float pj[64][64];
  __shared__ float wsh[64][65];
  const int h = blockIdx.x, c0 = blockIdx.y*64;
  const int tid = threadIdx.x, lane = tid&63, tg = tid>>6;
  for (int i=tid; i<4096; i+=256) pj[i>>6][i&63] = proj[i];
  for (int i=tg; i<64; i+=4) wsh[i][lane] = w[(size_t)(c0+i)*512 + h*64 + lane];
  __syncthreads();
  float acc[16];
  #pragma unroll
  for (int j=0;j<16;j++) acc[j]=0.f;
  for (int d=0; d<64; ++d){
    float wv = wsh[lane][d];
    #pragma unroll
    for (int j=0;j<16;j++) acc[j] += wv * pj[tg*16+j][d];
  }
  #pragma unroll
  for (int j=0;j<16;j++)
    Wcat[(size_t)(mapbase + h*64 + tg*16 + j)*512 + c0 + lane] = __float2bfloat16(acc[j]*NORM_);
}

// bias pack for the 1536-col layout: [bqp(512) | bkp(512) | bv(512)]
__global__ void bpack_k(const float* __restrict__ bq, const float* __restrict__ bk,
                        const float* __restrict__ bv, const float* __restrict__ proj,
                        float* __restrict__ bl)
{
  int idx = blockIdx.x*256 + threadIdx.x;
  if (idx >= 1536) return;
  float v;
  if (idx < 1024){
    const float* bsrc = (idx<512)? bq : bk;
    int t = idx & 511;
    int h = t>>6, m = t&63;
    float acc=0.f;
    for (int d=0; d<64; ++d) acc += bsrc[h*64+d]*proj[m*64+d];
    v = acc*NORM_;
  } else v = bv[idx-1024];
  bl[idx] = v;
}

// invm2[m] = 1 / sum_d proj[m][d]^2   (proj row norms = mult_m)
__global__ void invm_k(const float* __restrict__ proj, float* __restrict__ invm2)
{
  int m = threadIdx.x;
  if (m < 64){
    float s = 0.f;
    for (int d=0; d<64; ++d){ float p = proj[m*64+d]; s += p*p; }
    invm2[m] = 1.f/s;
  }
}

// ---------------- LayerNorm (bf16 in, bf16 out, grid-stride) ---------------
__global__ __launch_bounds__(256)
void ln_k(const bf16* __restrict__ x, const float* __restrict__ g,
          const float* __restrict__ b, bf16* __restrict__ y, int nrows)
{
  const int wid = threadIdx.x>>6, lane = threadIdx.x&63;
  float gv[8], bv[8];
  {
    float4 t0 = *(const float4*)(g + lane*8);
    float4 t1 = *(const float4*)(g + lane*8 + 4);
    gv[0]=t0.x;gv[1]=t0.y;gv[2]=t0.z;gv[3]=t0.w;gv[4]=t1.x;gv[5]=t1.y;gv[6]=t1.z;gv[7]=t1.w;
    float4 u0 = *(const float4*)(b + lane*8);
    float4 u1 = *(const float4*)(b + lane*8 + 4);
    bv[0]=u0.x;bv[1]=u0.y;bv[2]=u0.z;bv[3]=u0.w;bv[4]=u1.x;bv[5]=u1.y;bv[6]=u1.z;bv[7]=u1.w;
  }
  for (size_t row = (size_t)blockIdx.x*4 + wid; row < (size_t)nrows; row += (size_t)gridDim.x*4){
    bf16x8 xv = *(const bf16x8*)(x + row*D_ + lane*8);
    float f[8];
    #pragma unroll
    for (int j=0;j<8;j++) f[j] = bf2f((unsigned short)xv[j]);
    float s=0.f, ss=0.f;
    #pragma unroll
    for (int j=0;j<8;j++){ s += f[j]; ss += f[j]*f[j]; }
    #pragma unroll
    for (int o=32;o;o>>=1){ s += __shfl_xor(s,o); ss += __shfl_xor(ss,o); }
    const float mean = s*(1.f/D_);
    const float rstd = rsqrtf(ss*(1.f/D_) - mean*mean + 1e-5f);
    union { bf16 bb[8]; bf16x8 v8; } o8;
    #pragma unroll
    for (int j=0;j<8;j++)
      o8.bb[j] = __float2bfloat16((f[j]-mean)*rstd*gv[j] + bv[j]);
    *(bf16x8*)(y + row*D_ + lane*8) = o8.v8;
  }
}

// ------- fused featK + kps + ctx: stab-free ---------------------------------
__global__ __launch_bounds__(256)
void fctx_k(const bf16* __restrict__ ddk, const bf16* __restrict__ vbf,
            float* __restrict__ ctx, float* __restrict__ kps)
{
  __shared__ float kc[32][64], vc[32][64];
  const int bh = blockIdx.x, tid = threadIdx.x;
  const int b = bh>>3, h = bh&7;
  const int mq = tid>>4, dq = tid&15;
  const int cc = (tid&15)*4;
  f32x2 acc2[2][4];
  #pragma unroll
  for (int p=0;p<2;p++)
    #pragma unroll
    for (int j=0;j<4;j++) acc2[p][j] = (f32x2){0.f,0.f};
  float kpart[4] = {0.f,0.f,0.f,0.f};
  for (int s0=0; s0<S_; s0+=32){
    #pragma unroll
    for (int ii=0; ii<2; ++ii){
      const int rr = (tid>>4) + ii*16;
      const size_t grow = (size_t)(b*S_+s0+rr)*512 + h*64 + cc;
      ushort4 du = *(const ushort4*)(ddk + grow);
      float4 kv;
      kv.x = 0.125f*(__expf(bf2f(du.x))+1e-4f);
      kv.y = 0.125f*(__expf(bf2f(du.y))+1e-4f);
      kv.z = 0.125f*(__expf(bf2f(du.z))+1e-4f);
      kv.w = 0.125f*(__expf(bf2f(du.w))+1e-4f);
      *(float4*)&kc[rr][cc] = kv;
      kpart[0]+=kv.x; kpart[1]+=kv.y; kpart[2]+=kv.z; kpart[3]+=kv.w;
      ushort4 vu = *(const ushort4*)(vbf + grow);
      float4 vv;
      vv.x = bf2f(vu.x); vv.y = bf2f(vu.y);
      vv.z = bf2f(vu.z); vv.w = bf2f(vu.w);
      *(float4*)&vc[rr][cc] = vv;
    }
    __syncthreads();
    #pragma unroll 8
    for (int ssi=0; ssi<32; ++ssi){
      f32x2 a0 = *(const f32x2*)&kc[ssi][mq*4 + 0];
      f32x2 a1 = *(const f32x2*)&kc[ssi][mq*4 + 2];
      float4 b4 = *(const float4*)&vc[ssi][dq*4];
      acc2[0][0] += a0 * (f32x2){b4.x,b4.x};
      acc2[0][1] += a0 * (f32x2){b4.y,b4.y};
      acc2[0][2] += a0 * (f32x2){b4.z,b4.z};
      acc2[0][3] += a0 * (f32x2){b4.w,b4.w};
      acc2[1][0] += a1 * (f32x2){b4.x,b4.x};
      acc2[1][1] += a1 * (f32x2){b4.y,b4.y};
      acc2[1][2] += a1 * (f32x2){b4.z,b4.z};
      acc2[1][3] += a1 * (f32x2){b4.w,b4.w};
    }
    __syncthreads();
  }
  #pragma unroll
  for (int p=0;p<2;p++)
    #pragma unroll
    for (int j=0;j<4;j++){
      ctx[((size_t)bh*64 + mq*4 + 2*p    )*64 + dq*4+j] = acc2[p][j].x;
      ctx[((size_t)bh*64 + mq*4 + 2*p + 1)*64 + dq*4+j] = acc2[p][j].y;
    }
  float* kcf = &kc[0][0];
  #pragma unroll
  for (int j=0;j<4;j++) kcf[tid*4+j] = kpart[j];
  __syncthreads();
  if (tid < 64){
    const int m = tid;
    float s = 0.f;
    #pragma unroll
    for (int g=0; g<16; ++g) s += kcf[(g*16 + (m>>2))*4 + (m&3)];
    kps[bh*64 + m] = s;
  }
}

// ------- attn out: wave-local qL (no per-iter barriers) --------------------
__global__ __launch_bounds__(256)
void attnout_k(const bf16* __restrict__ qpb, const float* __restrict__ ctx,
               const float* __restrict__ kps, bf16* __restrict__ out)
{
  __shared__ float cl[4096];
  __shared__ float kl[64];
  __shared__ float qL[4][64];
  const int bh = blockIdx.x, tid = threadIdx.x;
  for (int i=tid;i<4096;i+=256) cl[i] = ctx[(size_t)bh*4096 + i];
  if (tid<64) kl[tid] = kps[bh*64+tid];
  __syncthreads();
  const int b = bh>>3, h = bh&7;
  const int d = tid&63, sg = tid>>6;
  const int send = min((int)(blockIdx.y*64+64), S_);
  for (int s0 = blockIdx.y*64; s0 < send; s0 += 4){
    const int sr = s0 + sg;
    const size_t rrow = (size_t)(b*S_+sr);
    float qp = bf2f(*(const unsigned short*)&qpb[rrow*512 + h*64 + d]);
    qL[sg][d] = qp;
    float a0=0,a1=0,a2=0,a3=0, e0=0,e1=0,e2=0,e3=0;
    #pragma unroll
    for (int m=0;m<64;m+=4){
      float q0=qL[sg][m], q1=qL[sg][m+1], q2=qL[sg][m+2], q3=qL[sg][m+3];
      a0 += q0*cl[(m  )*64+d]; a1 += q1*cl[(m+1)*64+d];
      a2 += q2*cl[(m+2)*64+d]; a3 += q3*cl[(m+3)*64+d];
      e0 += q0*kl[m]; e1 += q1*kl[m+1]; e2 += q2*kl[m+2]; e3 += q3*kl[m+3];
    }
    const float den = (e0+e1)+(e2+e3);
    const float o = ((a0+a1)+(a2+a3))/den;
    out[(rrow*H_ + h)*64 + d] = __float2bfloat16(o);
  }
}

// ---------------- head (bf16 h) --------------------------------------------
__global__ __launch_bounds__(256)
void head_k(const bf16* __restrict__ h, const float* __restrict__ fcw,
            const float* __restrict__ fcb, float* __restrict__ out)
{
  __shared__ float red[256][2];
  const int b = blockIdx.x, tid = threadIdx.x;
  const bf16* hb = h + (size_t)b*S_*D_;
  float s0=0.f, s1=0.f;
  for (int s=0; s<S_; ++s){
    s0 += bf2f(*(const unsigned short*)&hb[(size_t)s*D_ + tid]);
    s1 += bf2f(*(const unsigned short*)&hb[(size_t)s*D_ + tid + 256]);
  }
  const float m0 = s0*(1.f/S_), m1 = s1*(1.f/S_);
  red[tid][0] = m0*fcw[tid*2+0] + m1*fcw[(tid+256)*2+0];
  red[tid][1] = m0*fcw[tid*2+1] + m1*fcw[(tid+256)*2+1];
  __syncthreads();
  for (int st=128; st; st>>=1){
    if (tid<st){ red[tid][0]+=red[tid+st][0]; red[tid][1]+=red[tid+st][1]; }
    __syncthreads();
  }
  if (tid==0){ out[b*2+0]=red[0][0]+fcb[0]; out[b*2+1]=red[0][1]+fcb[1]; }
}

extern "C" void kernel_launch(void* const* d_in, const int* in_sizes, int n_in,
                              void* d_out, int out_size, void* d_ws, size_t ws_size,
                              hipStream_t stream)
{
  const float* x     = (const float*)d_in[0];
  const float* emb_w = (const float*)d_in[1];
  const float* emb_b = (const float*)d_in[2];
  const float* pos   = (const float*)d_in[3];
  const float* ln1_g = (const float*)d_in[4];
  const float* ln1_b = (const float*)d_in[5];
  const float* wq    = (const float*)d_in[6];
  const float* bq    = (const float*)d_in[7];
  const float* wk    = (const float*)d_in[8];
  const float* bk    = (const float*)d_in[9];
  const float* wv    = (const float*)d_in[10];
  const float* bv    = (const float*)d_in[11];
  const float* wo    = (const float*)d_in[12];
  const float* bo    = (const float*)d_in[13];
  const float* proj  = (const float*)d_in[14];
  const float* ln2_g = (const float*)d_in[15];
  const float* ln2_b = (const float*)d_in[16];
  const float* w1    = (const float*)d_in[17];
  const float* b1    = (const float*)d_in[18];
  const float* w2    = (const float*)d_in[19];
  const float* b2    = (const float*)d_in[20];
  const float* fc_w  = (const float*)d_in[21];
  const float* fc_b  = (const float*)d_in[22];
  float* out = (float*)d_out;

  const size_t W55 = (size_t)512*512, W52 = (size_t)512*2048;
  const size_t WCAT = (size_t)1536*512;

  char* p = (char*)d_ws;
  auto take = [&](size_t bytes)->char*{
    char* r = p; p += (bytes + 255) & ~(size_t)255; return r;
  };
  bf16* Wcat = (bf16*)take(L_*WCAT*2);
  bf16* woT  = (bf16*)take(L_*W55*2);
  bf16* w1T  = (bf16*)take(L_*W52*2);
  bf16* w2T  = (bf16*)take(L_*W52*2);
  bf16* embT = (bf16*)take((size_t)64*512*2);
  bf16* xbf  = (bf16*)take((size_t)B_*S_*DIN_*2);
  bf16* posbf= (bf16*)take((size_t)S_*512*2);
  float* bcat= (float*)take(L_*1536*4);
  float* invm= (float*)take(L_*64*4);
  const size_t fixed_bytes = (size_t)(p - (char*)d_ws);

  // NB=32, FFN in 2 row-chunks: working set ~190 MB < 256 MB L3 ->
  // the hidden write->read round-trip becomes cache-resident.
  int NB = 32; size_t need = 0;
  for (;; NB >>= 1){
    size_t RC = (size_t)NB*S_, nbh = (size_t)NB*H_;
    need = fixed_bytes + RC*(5*1024 + 2048) + nbh*(16384+256) + 65536;
    if (need <= ws_size || NB == 1) break;
  }
  if (need > ws_size) return;
  const size_t RC = (size_t)NB*S_;
  const int NBH = NB*H_, rows = (int)RC;

  bf16*  hbuf = (bf16*)take(RC*512*2);    // residual stream bf16
  bf16*  qpb  = (bf16*)take(RC*512*2);    // qp
  bf16*  ddk  = (bf16*)take(RC*512*2);    // ddk' (bf16)
  bf16*  vbf  = (bf16*)take(RC*512*2);    // v
  bf16*  ybf  = (bf16*)take(RC*512*2);
  bf16*  hidbf= (bf16*)take(RC*1024*2);   // FFN hidden: HALF-row chunk (52 MB)
  float* ctx  = (float*)take((size_t)NBH*4096*4);
  float* kps  = (float*)take((size_t)NBH*64*4);

  dim3 blk(256), blk5(512);

  // ---- per-launch weight prep ----
  for (int l=0; l<L_; ++l){
    bf16* Wl = Wcat + (size_t)l*WCAT;
    float* bl = bcat + (size_t)l*1536;
    projw_k<<<dim3(8,8),   blk, 0, stream>>>(wq + l*W55, proj + l*4096, Wl, 0);
    projw_k<<<dim3(8,8),   blk, 0, stream>>>(wk + l*W55, proj + l*4096, Wl, 512);
    convT_k<<<dim3(16,16), blk, 0, stream>>>(wv + l*W55, Wl, 512, 512, 1024, 64);
    bpack_k<<<6, blk, 0, stream>>>(bq + l*512, bk + l*512, bv + l*512, proj + l*4096, bl);
    invm_k<<<1, 64, 0, stream>>>(proj + l*4096, invm + l*64);
    convT_k<<<dim3(16,16), blk, 0, stream>>>(wo + l*W55, woT + l*W55, 512, 512, 0, 64);
    convT_k<<<dim3(64,16), blk, 0, stream>>>(w1 + l*W52, w1T + l*W52, 512, 2048, 0, 64);
    convT_k<<<dim3(16,64), blk, 0, stream>>>(w2 + l*W52, w2T + l*W52, 2048, 512, 0, 64);
  }
  convT_k<<<dim3(16,2), blk, 0, stream>>>(emb_w, embT, 64, 512, 0, 64);
  conv_k<<<(B_*S_*DIN_/4 + 255)/256, blk, 0, stream>>>(x, xbf, B_*S_*DIN_/4);
  conv_k<<<(S_*512/4 + 255)/256, blk, 0, stream>>>(pos, posbf, S_*512/4);

  const int rg128 = (rows + 127)/128;
  const int rg256 = (rows + 255)/256;
  const int crows = rows/2;                 // FFN row-chunk
  const int cg256 = (crows + 255)/256;

  for (int bc = 0; bc < B_/NB; ++bc){
    const bf16* xc = xbf + (size_t)bc*RC*DIN_;
    float* outc = out + (size_t)bc*NB*2;

    gemm2_k<0,1,1><<<4*rg128, blk, 0, stream>>>(
        xc, embT, emb_b, posbf, nullptr, hbuf, rows, 512, 64, S_, 4);

    for (int l=0; l<L_; ++l){
      ln_k<<<2048, blk, 0, stream>>>(hbuf, ln1_g + l*512, ln1_b + l*512, ybf, rows);
      mega256_k<<<6*rg256, blk5, 0, stream>>>(
          ybf, Wcat + (size_t)l*WCAT, bcat + (size_t)l*1536, invm + l*64, rows,
          qpb, ddk, vbf, 6);
      fctx_k<<<NBH, blk, 0, stream>>>(ddk, vbf, ctx, kps);
      attnout_k<<<dim3(NBH, (S_+63)/64), blk, 0, stream>>>(qpb, ctx, kps, ybf);
      gemm256_k<0,1,1><<<2*rg256, blk5, 0, stream>>>(
          ybf, woT + l*W55, bo + l*512, hbuf, nullptr, hbuf, rows, 512, 512, 2);
      ln_k<<<2048, blk, 0, stream>>>(hbuf, ln2_g + l*512, ln2_b + l*512, ybf, rows);
      for (int c=0; c<2; ++c){
        bf16* ybc = ybf  + (size_t)c*crows*512;
        bf16* hbc = hbuf + (size_t)c*crows*512;
        gemm256_k<1,0,1><<<8*cg256, blk5, 0, stream>>>(
            ybc, w1T + l*W52, b1 + l*2048, nullptr, nullptr, hidbf, crows, 2048, 512, 8);
        gemm256_k<0,1,1><<<2*cg256, blk5, 0, stream>>>(
            hidbf, w2T + l*W52, b2 + l*512, hbc, nullptr, hbc, crows, 512, 2048, 2);
      }
    }
    head_k<<<NB, blk, 0, stream>>>(hbuf, fc_w, fc_b, outc);
  }
}

// Round 17
// 1674.550 us; speedup vs baseline: 1.3017x; 1.3017x over previous
//
#include <hip/hip_runtime.h>
#include <hip/hip_bf16.h>

#define B_   64
#define S_   800
#define DIN_ 64
#define D_   512
#define H_   8
#define DH_  64
#define M_   64
#define L_   2
#define FF_  2048

typedef __hip_bfloat16 bf16;
typedef __attribute__((ext_vector_type(8))) short bf16x8;
typedef __attribute__((ext_vector_type(4))) float f32x4;
typedef __attribute__((ext_vector_type(2))) float f32x2;

#define NORM_ 0.35355339059327373f   // 64^(-1/4)

__device__ __forceinline__ float bf2f(unsigned short s){
  return __uint_as_float(((unsigned)s)<<16);
}
// tanh-approx GELU with hardware exp: tanh(u) = 1 - 2/(1+e^{2u}).
__device__ __forceinline__ float gelu_f(float x){
  float u = 0.7978845608028654f*(x + 0.044715f*x*x*x);
  float e = __expf(2.f*u);
  float t = 1.f - 2.f/(1.f + e);
  return 0.5f*x*(1.f + t);
}
__device__ __forceinline__ void st_bf4(bf16* p, float4 v){
  union { bf16 b[4]; unsigned long long u; } q;
  q.b[0]=__float2bfloat16(v.x); q.b[1]=__float2bfloat16(v.y);
  q.b[2]=__float2bfloat16(v.z); q.b[3]=__float2bfloat16(v.w);
  *(unsigned long long*)p = q.u;
}
__device__ __forceinline__ void gld16(const void* g, void* l){
  __builtin_amdgcn_global_load_lds((const __attribute__((address_space(1))) void*)g,
                                   (__attribute__((address_space(3))) void*)l, 16, 0, 0);
}

// XCD-chunked bijective block swizzle (m204)
__device__ __forceinline__ void swz_xy(int gx, int& bx, int& by){
  const int nwg = (int)gridDim.x, orig = (int)blockIdx.x;
  const int q = nwg>>3, r = nwg&7;
  const int xcd = orig&7, lin = orig>>3;
  const int wg = (xcd<r ? xcd*(q+1) : r*(q+1)+(xcd-r)*q) + lin;
  bx = wg % gx;  by = wg / gx;
}

// ================= 256x256 / BK=64 tile core (dbuf, known-good) ============
__device__ __forceinline__ void gemm_tile256(const bf16* __restrict__ A,
                                             const bf16* __restrict__ Wt,
                                             int rows, int K, int bx, int by,
                                             f32x4 (&acc)[8][4])
{
  __shared__ bf16 As[2][16384];
  __shared__ bf16 Bs[2][16384];
  const int tid = threadIdx.x, wave = tid>>6, lane = tid&63;
  const int wr = wave>>2, wc = wave&3;
  const int lr = lane&15, hi = lane>>4;
  const int row0 = by*256, col0 = bx*256;
  const int srow = tid>>3;
  const int scol = ((tid&7) ^ ((srow>>1)&7))*8;  // pre-swizzled source chunk
  const int keyq = (lr>>1)&7;                    // read-side XOR key
  const bf16* gA[4]; const bf16* gB[4];
  #pragma unroll
  for (int i=0;i<4;i++){
    const int ra = min(row0 + i*64 + srow, rows-1);
    gA[i] = A  + (size_t)ra*K + scol;
    gB[i] = Wt + (size_t)(col0 + i*64 + srow)*K + scol;
  }
  const int dbase = wave*512;
  const int NT = K>>6;
  #pragma unroll
  for (int i=0;i<4;i++){
    gld16(gA[i], &As[0][i*4096 + dbase]);
    gld16(gB[i], &Bs[0][i*4096 + dbase]);
  }
  __syncthreads();
  for (int t=0; t<NT; ++t){
    const int p = t&1;
    if (t+1 < NT){
      const int k0 = (t+1)<<6;
      #pragma unroll
      for (int i=0;i<4;i++){
        gld16(gA[i] + k0, &As[p^1][i*4096 + dbase]);
        gld16(gB[i] + k0, &Bs[p^1][i*4096 + dbase]);
      }
    }
    #pragma unroll
    for (int ks=0; ks<2; ++ks){
      const int co = ((ks*4 + hi) ^ keyq)*8;
      bf16x8 af[8], bv[4];
      #pragma unroll
      for (int mi=0;mi<8;mi++)
        af[mi] = *(const bf16x8*)&As[p][(wr*128 + mi*16 + lr)*64 + co];
      #pragma unroll
      for (int ni=0;ni<4;ni++)
        bv[ni] = *(const bf16x8*)&Bs[p][(wc*64 + ni*16 + lr)*64 + co];
      #pragma unroll
      for (int mi=0;mi<8;mi++)
        #pragma unroll
        for (int ni=0;ni<4;ni++)
          acc[mi][ni] = __builtin_amdgcn_mfma_f32_16x16x32_bf16(af[mi], bv[ni], acc[mi][ni], 0,0,0);
    }
    __syncthreads();
  }
}

// ---------------- standard 256-tile GEMM (res/out bf16) --------------------
template<int ACT, int RES, int OUTB>
__global__ __launch_bounds__(512,2)
void gemm256_k(const bf16* __restrict__ A, const bf16* __restrict__ Wt,
               const float* __restrict__ bias, const bf16* __restrict__ res,
               float* __restrict__ Cf, bf16* __restrict__ Cb,
               int rows, int N, int K, int gx)
{
  int bx, by;  swz_xy(gx, bx, by);
  f32x4 acc[8][4];
  #pragma unroll
  for (int i=0;i<8;i++)
    #pragma unroll
    for (int j=0;j<4;j++) acc[i][j] = (f32x4){0.f,0.f,0.f,0.f};
  gemm_tile256(A, Wt, rows, K, bx, by, acc);
  const int tid=threadIdx.x, wave=tid>>6, lane=tid&63;
  const int wr=wave>>2, wc=wave&3, lr=lane&15, hi=lane>>4;
  const int row0=by*256, col0=bx*256;
  #pragma unroll
  for (int mi=0;mi<8;mi++){
    #pragma unroll
    for (int i=0;i<4;i++){
      const int r = row0 + wr*128 + mi*16 + hi*4 + i;
      if (r >= rows) continue;
      #pragma unroll
      for (int ni=0;ni<4;ni++){
        const int c = col0 + wc*64 + ni*16 + lr;
        float v = acc[mi][ni][i] + bias[c];
        if (ACT) v = gelu_f(v);
        if (RES) v += bf2f(*(const unsigned short*)&res[(size_t)r*N + c]);
        if (OUTB) Cb[(size_t)r*N + c] = __float2bfloat16(v);
        else      Cf[(size_t)r*N + c] = v;
      }
    }
  }
}

// ---------------- mega 256-tile GEMM: N=1536 [ddq|ddk|v] -------------------
// Stabilizer-free; diag reconstructed from dd via invm2 (proj = D·Q^T).
__global__ __launch_bounds__(512,1)
void mega256_k(const bf16* __restrict__ A, const bf16* __restrict__ Wcat,
               const float* __restrict__ bcat, const float* __restrict__ invm2,
               int rows,
               bf16* __restrict__ qpb, bf16* __restrict__ ddk,
               bf16* __restrict__ vbf, int gx)
{
  int bx, by;  swz_xy(gx, bx, by);
  f32x4 acc[8][4];
  #pragma unroll
  for (int i=0;i<8;i++)
    #pragma unroll
    for (int j=0;j<4;j++) acc[i][j] = (f32x4){0.f,0.f,0.f,0.f};
  gemm_tile256(A, Wcat, rows, 512, bx, by, acc);
  const int tid=threadIdx.x, wave=tid>>6, lane=tid&63;
  const int wr=wave>>2, wc=wave&3, lr=lane&15, hi=lane>>4;
  const int row0 = by*256;
  const int cbase = bx*256 + wc*64;
  float bb[4];
  #pragma unroll
  for (int ni=0;ni<4;ni++) bb[ni] = bcat[cbase + ni*16 + lr];

  if (bx < 4){                       // dd sections
    const int isK = bx>>1;
    const int h = (bx&1)*4 + wc;
    float im[4];
    #pragma unroll
    for (int ni=0;ni<4;ni++) im[ni] = invm2[ni*16 + lr];
    float ds[32];
    #pragma unroll
    for (int mi=0;mi<8;mi++)
      #pragma unroll
      for (int i=0;i<4;i++){
        float v0=acc[mi][0][i]+bb[0], v1=acc[mi][1][i]+bb[1];
        float v2=acc[mi][2][i]+bb[2], v3=acc[mi][3][i]+bb[3];
        ds[mi*4+i] = v0*v0*im[0] + v1*v1*im[1] + v2*v2*im[2] + v3*v3*im[3];
      }
    #pragma unroll
    for (int st=1; st<=8; st<<=1)
      #pragma unroll
      for (int idx=0;idx<32;idx++) ds[idx] += __shfl_xor(ds[idx], st);
    #pragma unroll
    for (int mi=0;mi<8;mi++){
      #pragma unroll
      for (int i=0;i<4;i++){
        const int r = row0 + wr*128 + mi*16 + hi*4 + i;
        if (r >= rows) continue;
        const float dg = 0.5f*ds[mi*4+i];
        if (!isK){
          #pragma unroll
          for (int ni=0;ni<4;ni++)
            qpb[(size_t)r*512 + h*64 + ni*16 + lr] =
                __float2bfloat16(0.125f*(__expf(acc[mi][ni][i]+bb[ni] - dg) + 1e-4f));
        } else {
          #pragma unroll
          for (int ni=0;ni<4;ni++)
            ddk[(size_t)r*512 + h*64 + ni*16 + lr] =
                __float2bfloat16(acc[mi][ni][i]+bb[ni] - dg);
        }
      }
    }
  } else {                           // v section
    const int colb = (bx-4)*256 + wc*64;
    #pragma unroll
    for (int mi=0;mi<8;mi++){
      #pragma unroll
      for (int i=0;i<4;i++){
        const int r = row0 + wr*128 + mi*16 + hi*4 + i;
        if (r >= rows) continue;
        #pragma unroll
        for (int ni=0;ni<4;ni++)
          vbf[(size_t)r*512 + colb + ni*16 + lr] =
              __float2bfloat16(acc[mi][ni][i] + bb[ni]);
      }
    }
  }
}

// ================= old 128x128 core (embed only, K=64) =====================
__device__ __forceinline__ void gemm_tile(const bf16* __restrict__ A,
                                          const bf16* __restrict__ Wt,
                                          int rows, int K, int bx, int by,
                                          f32x4 (&acc)[4][4])
{
  __shared__ bf16 As[3*4096];
  __shared__ bf16 Bs[3*4096];
  const int tid = threadIdx.x, wave = tid>>6, lane = tid&63;
  const int row0 = by*128, col0 = bx*128;
  const int wm = (wave>>1)*64, wn = (wave&1)*64;
  const int lr = lane&15;
  const int lk = ((lane>>4) ^ ((lane>>1)&3))*8;
  const int c0 = wave*2, c1 = c0+1;
  const int sub = lane>>2;
  const int kq = (((lane&3) ^ ((lane>>3)&3)))*8;
  const int ra0 = min(row0 + c0*16 + sub, rows-1);
  const int ra1 = min(row0 + c1*16 + sub, rows-1);
  const bf16* gA0 = A + (size_t)ra0*K + kq;
  const bf16* gA1 = A + (size_t)ra1*K + kq;
  const bf16* gB0 = Wt + (size_t)(col0 + c0*16 + sub)*K + kq;
  const bf16* gB1 = Wt + (size_t)(col0 + c1*16 + sub)*K + kq;
  const int o0 = c0*512, o1 = c1*512;
  const int nt = K>>5;
  gld16(gA0, &As[o0]);  gld16(gA1, &As[o1]);
  gld16(gB0, &Bs[o0]);  gld16(gB1, &Bs[o1]);
  __syncthreads();
  int cur = 0;
  for (int t=0; t<nt; ++t){
    const int nxt = (cur+4096 > 8192) ? 0 : cur+4096;
    if (t+1 < nt){
      const int k0 = (t+1)*32;
      gld16(gA0+k0, &As[nxt+o0]);  gld16(gA1+k0, &As[nxt+o1]);
      gld16(gB0+k0, &Bs[nxt+o0]);  gld16(gB1+k0, &Bs[nxt+o1]);
    }
    bf16x8 af[4], bv[4];
    #pragma unroll
    for (int mi=0;mi<4;mi++) af[mi] = *(const bf16x8*)&As[cur + (wm+mi*16+lr)*32 + lk];
    #pragma unroll
    for (int ni=0;ni<4;ni++) bv[ni] = *(const bf16x8*)&Bs[cur + (wn+ni*16+lr)*32 + lk];
    #pragma unroll
    for (int mi=0;mi<4;mi++)
      #pragma unroll
      for (int ni=0;ni<4;ni++)
        acc[mi][ni] = __builtin_amdgcn_mfma_f32_16x16x32_bf16(af[mi], bv[ni], acc[mi][ni], 0,0,0);
    __syncthreads();
    cur = nxt;
  }
}

template<int ACT, int RES, int OUTB>
__global__ __launch_bounds__(256)
void gemm2_k(const bf16* __restrict__ A, const bf16* __restrict__ Wt,
             const float* __restrict__ bias, const bf16* __restrict__ res,
             float* __restrict__ Cf, bf16* __restrict__ Cb,
             int rows, int N, int K, int res_mod, int gx)
{
  int bx, by;  swz_xy(gx, bx, by);
  f32x4 acc[4][4];
  #pragma unroll
  for (int i=0;i<4;i++)
    #pragma unroll
    for (int j=0;j<4;j++) acc[i][j] = (f32x4){0.f,0.f,0.f,0.f};
  gemm_tile(A, Wt, rows, K, bx, by, acc);
  const int tid=threadIdx.x, wave=tid>>6, lane=tid&63;
  const int wm=(wave>>1)*64, wn=(wave&1)*64, lr=lane&15, hi=lane>>4;
  const int row0=by*128, col0=bx*128;
  #pragma unroll
  for (int mi=0;mi<4;mi++){
    #pragma unroll
    for (int i=0;i<4;i++){
      const int r = row0 + wm + mi*16 + hi*4 + i;
      if (r >= rows) continue;
      #pragma unroll
      for (int ni=0;ni<4;ni++){
        const int c = col0 + wn + ni*16 + lr;
        float v = acc[mi][ni][i] + bias[c];
        if (ACT) v = gelu_f(v);
        if (RES) v += bf2f(*(const unsigned short*)&res[(size_t)(res_mod ? (r % res_mod) : r)*N + c]);
        if (OUTB) Cb[(size_t)r*N + c] = __float2bfloat16(v);
        else      Cf[(size_t)r*N + c] = v;
      }
    }
  }
}

// ------- weight transpose+convert with column remap ------------------------
__global__ __launch_bounds__(256)
void convT_k(const float* __restrict__ src, bf16* __restrict__ dst, int K, int N,
             int mapbase, int mapstride)
{
  __shared__ float t[32][33];
  const int n0 = blockIdx.x*32, k0 = blockIdx.y*32;
  const int j = threadIdx.x&31, i0 = threadIdx.x>>5;
  #pragma unroll
  for (int i=i0; i<32; i+=8) t[i][j] = src[(size_t)(k0+i)*N + n0 + j];
  __syncthreads();
  #pragma unroll
  for (int i=i0; i<32; i+=8){
    const int n = n0 + i;
    const int rn = mapbase + (n>>6)*mapstride + (n&63);
    dst[(size_t)rn*K + k0 + j] = __float2bfloat16(t[j][i]);
  }
}

__global__ void conv_k(const float* __restrict__ src, bf16* __restrict__ dst, int n4)
{
  int i = blockIdx.x*256 + threadIdx.x;
  if (i < n4){ float4 v = ((const float4*)src)[i]; st_bf4(dst + (size_t)i*4, v); }
}

// folded feature weight into Wcat: out row = mapbase + h*64 + m
__global__ __launch_bounds__(256)
void projw_k(const float* __restrict__ w, const float* __restrict__ proj,
             bf16* __restrict__ Wcat, int mapbase)
{
  __shared__ float pj[64][64];
  __shared__ float wsh[64][65];
  const int h = blockIdx.x, c0 = blockIdx.y*64;
  const int tid = threadIdx.x, lane = tid&63, tg = tid>>6;
  for (int i=tid; i<4096; i+=256) pj[i>>6][i&63] = proj[i];
  for (int i=tg; i<64; i+=4) wsh[i][lane] = w[(size_t)(c0+i)*512 + h*64 + lane];
  __syncthreads();
  float acc[16];
  #pragma unroll
  for (int j=0;j<16;j++) acc[j]=0.f;
  for (int d=0; d<64; ++d){
    float wv = wsh[lane][d];
    #pragma unroll
    for (int j=0;j<16;j++) acc[j] += wv * pj[tg*16+j][d];
  }
  #pragma unroll
  for (int j=0;j<16;j++)
    Wcat[(size_t)(mapbase + h*64 + tg*16 + j)*512 + c0 + lane] = __float2bfloat16(acc[j]*NORM_);
}

// bias pack for the 1536-col layout: [bqp(512) | bkp(512) | bv(512)]
__global__ void bpack_k(const float* __restrict__ bq, const float* __restrict__ bk,
                        const float* __restrict__ bv, const float* __restrict__ proj,
                        float* __restrict__ bl)
{
  int idx = blockIdx.x*256 + threadIdx.x;
  if (idx >= 1536) return;
  float v;
  if (idx < 1024){
    const float* bsrc = (idx<512)? bq : bk;
    int t = idx & 511;
    int h = t>>6, m = t&63;
    float acc=0.f;
    for (int d=0; d<64; ++d) acc += bsrc[h*64+d]*proj[m*64+d];
    v = acc*NORM_;
  } else v = bv[idx-1024];
  bl[idx] = v;
}

// invm2[m] = 1 / sum_d proj[m][d]^2   (proj row norms = mult_m)
__global__ void invm_k(const float* __restrict__ proj, float* __restrict__ invm2)
{
  int m = threadIdx.x;
  if (m < 64){
    float s = 0.f;
    for (int d=0; d<64; ++d){ float p = proj[m*64+d]; s += p*p; }
    invm2[m] = 1.f/s;
  }
}

// ---------------- LayerNorm (bf16 in, bf16 out, grid-stride) ---------------
__global__ __launch_bounds__(256)
void ln_k(const bf16* __restrict__ x, const float* __restrict__ g,
          const float* __restrict__ b, bf16* __restrict__ y, int nrows)
{
  const int wid = threadIdx.x>>6, lane = threadIdx.x&63;
  float gv[8], bv[8];
  {
    float4 t0 = *(const float4*)(g + lane*8);
    float4 t1 = *(const float4*)(g + lane*8 + 4);
    gv[0]=t0.x;gv[1]=t0.y;gv[2]=t0.z;gv[3]=t0.w;gv[4]=t1.x;gv[5]=t1.y;gv[6]=t1.z;gv[7]=t1.w;
    float4 u0 = *(const float4*)(b + lane*8);
    float4 u1 = *(const float4*)(b + lane*8 + 4);
    bv[0]=u0.x;bv[1]=u0.y;bv[2]=u0.z;bv[3]=u0.w;bv[4]=u1.x;bv[5]=u1.y;bv[6]=u1.z;bv[7]=u1.w;
  }
  for (size_t row = (size_t)blockIdx.x*4 + wid; row < (size_t)nrows; row += (size_t)gridDim.x*4){
    bf16x8 xv = *(const bf16x8*)(x + row*D_ + lane*8);
    float f[8];
    #pragma unroll
    for (int j=0;j<8;j++) f[j] = bf2f((unsigned short)xv[j]);
    float s=0.f, ss=0.f;
    #pragma unroll
    for (int j=0;j<8;j++){ s += f[j]; ss += f[j]*f[j]; }
    #pragma unroll
    for (int o=32;o;o>>=1){ s += __shfl_xor(s,o); ss += __shfl_xor(ss,o); }
    const float mean = s*(1.f/D_);
    const float rstd = rsqrtf(ss*(1.f/D_) - mean*mean + 1e-5f);
    union { bf16 bb[8]; bf16x8 v8; } o8;
    #pragma unroll
    for (int j=0;j<8;j++)
      o8.bb[j] = __float2bfloat16((f[j]-mean)*rstd*gv[j] + bv[j]);
    *(bf16x8*)(y + row*D_ + lane*8) = o8.v8;
  }
}

// ------- fused featK + kps + ctx^T (bf16): stab-free ------------------------
__global__ __launch_bounds__(256)
void fctx_k(const bf16* __restrict__ ddk, const bf16* __restrict__ vbf,
            bf16* __restrict__ ctxT, float* __restrict__ kps)
{
  __shared__ float kc[32][64], vc[32][64];
  const int bh = blockIdx.x, tid = threadIdx.x;
  const int b = bh>>3, h = bh&7;
  const int mq = tid>>4, dq = tid&15;
  const int cc = (tid&15)*4;
  f32x2 acc2[2][4];
  #pragma unroll
  for (int p=0;p<2;p++)
    #pragma unroll
    for (int j=0;j<4;j++) acc2[p][j] = (f32x2){0.f,0.f};
  float kpart[4] = {0.f,0.f,0.f,0.f};
  for (int s0=0; s0<S_; s0+=32){
    #pragma unroll
    for (int ii=0; ii<2; ++ii){
      const int rr = (tid>>4) + ii*16;
      const size_t grow = (size_t)(b*S_+s0+rr)*512 + h*64 + cc;
      ushort4 du = *(const ushort4*)(ddk + grow);
      float4 kv;
      kv.x = 0.125f*(__expf(bf2f(du.x))+1e-4f);
      kv.y = 0.125f*(__expf(bf2f(du.y))+1e-4f);
      kv.z = 0.125f*(__expf(bf2f(du.z))+1e-4f);
      kv.w = 0.125f*(__expf(bf2f(du.w))+1e-4f);
      *(float4*)&kc[rr][cc] = kv;
      kpart[0]+=kv.x; kpart[1]+=kv.y; kpart[2]+=kv.z; kpart[3]+=kv.w;
      ushort4 vu = *(const ushort4*)(vbf + grow);
      float4 vv;
      vv.x = bf2f(vu.x); vv.y = bf2f(vu.y);
      vv.z = bf2f(vu.z); vv.w = bf2f(vu.w);
      *(float4*)&vc[rr][cc] = vv;
    }
    __syncthreads();
    #pragma unroll 8
    for (int ssi=0; ssi<32; ++ssi){
      f32x2 a0 = *(const f32x2*)&kc[ssi][mq*4 + 0];
      f32x2 a1 = *(const f32x2*)&kc[ssi][mq*4 + 2];
      float4 b4 = *(const float4*)&vc[ssi][dq*4];
      acc2[0][0] += a0 * (f32x2){b4.x,b4.x};
      acc2[0][1] += a0 * (f32x2){b4.y,b4.y};
      acc2[0][2] += a0 * (f32x2){b4.z,b4.z};
      acc2[0][3] += a0 * (f32x2){b4.w,b4.w};
      acc2[1][0] += a1 * (f32x2){b4.x,b4.x};
      acc2[1][1] += a1 * (f32x2){b4.y,b4.y};
      acc2[1][2] += a1 * (f32x2){b4.z,b4.z};
      acc2[1][3] += a1 * (f32x2){b4.w,b4.w};
    }
    __syncthreads();
  }
  // store TRANSPOSED bf16: ctxT[d][m]  (MFMA B-operand layout for attnmm)
  #pragma unroll
  for (int p=0;p<2;p++)
    #pragma unroll
    for (int j=0;j<4;j++){
      const int d = dq*4 + j;
      ctxT[(size_t)bh*4096 + d*64 + mq*4 + 2*p    ] = __float2bfloat16(acc2[p][j].x);
      ctxT[(size_t)bh*4096 + d*64 + mq*4 + 2*p + 1] = __float2bfloat16(acc2[p][j].y);
    }
  float* kcf = &kc[0][0];
  #pragma unroll
  for (int j=0;j<4;j++) kcf[tid*4+j] = kpart[j];
  __syncthreads();
  if (tid < 64){
    const int m = tid;
    float s = 0.f;
    #pragma unroll
    for (int g=0; g<16; ++g) s += kcf[(g*16 + (m>>2))*4 + (m&3)];
    kps[bh*64 + m] = s;
  }
}

// ------- attn out via MFMA: out = (qp @ ctx^T^T)/(qp·kps) ------------------
// B rows 0..63 = ctxT[d][m]; row 64 = kps (bf16); rows 65..79 zero.
// den computed by the 5th N-fragment, broadcast via shfl from lane hi*16.
__global__ __launch_bounds__(256)
void attnmm_k(const bf16* __restrict__ qpb, const bf16* __restrict__ ctxT,
              const float* __restrict__ kps, bf16* __restrict__ out)
{
  __shared__ bf16 Bs[80*64];
  const int bh = blockIdx.x, tid = threadIdx.x;
  const int b = bh>>3, h = bh&7;
  for (int idx=tid; idx<640; idx+=256){
    const int row = idx>>3, q = idx&7;
    const int sq = q ^ ((row>>1)&7);          // pre-swizzled source chunk
    bf16x8 v;
    if (row < 64){
      v = *(const bf16x8*)(ctxT + (size_t)bh*4096 + row*64 + sq*8);
    } else if (row == 64){
      const float* kp = kps + bh*64 + sq*8;
      union { bf16 bb[8]; bf16x8 v8; } u;
      #pragma unroll
      for (int j=0;j<8;j++) u.bb[j] = __float2bfloat16(kp[j]);
      v = u.v8;
    } else {
      v = (bf16x8){0,0,0,0,0,0,0,0};
    }
    *(bf16x8*)(&Bs[row*64 + q*8]) = v;
  }
  __syncthreads();
  const int wave = tid>>6, lane = tid&63;
  const int lr = lane&15, hi = lane>>4;
  const int s0 = blockIdx.y*256 + wave*64;
  const int keyq = (lr>>1)&7;
  f32x4 acc[4][5];
  #pragma unroll
  for (int i=0;i<4;i++)
    #pragma unroll
    for (int j=0;j<5;j++) acc[i][j] = (f32x4){0.f,0.f,0.f,0.f};
  #pragma unroll
  for (int ks=0; ks<2; ++ks){
    bf16x8 af[4], bv[5];
    #pragma unroll
    for (int mi=0;mi<4;mi++){
      const int s = min(s0 + mi*16 + lr, S_-1);
      af[mi] = *(const bf16x8*)(qpb + (size_t)(b*S_+s)*512 + h*64 + ks*32 + hi*8);
    }
    #pragma unroll
    for (int ni=0;ni<5;ni++)
      bv[ni] = *(const bf16x8*)&Bs[(ni*16+lr)*64 + ((ks*4+hi)^keyq)*8];
    #pragma unroll
    for (int mi=0;mi<4;mi++)
      #pragma unroll
      for (int ni=0;ni<5;ni++)
        acc[mi][ni] = __builtin_amdgcn_mfma_f32_16x16x32_bf16(af[mi], bv[ni], acc[mi][ni], 0,0,0);
  }
  #pragma unroll
  for (int mi=0;mi<4;mi++){
    #pragma unroll
    for (int i=0;i<4;i++){
      const float den = __shfl(acc[mi][4][i], (lane & 48));
      const float inv = 1.f/den;
      const int s = s0 + mi*16 + hi*4 + i;
      if (s >= S_) continue;
      const size_t rrow = (size_t)(b*S_+s);
      #pragma unroll
      for (int ni=0;ni<4;ni++)
        out[(rrow*H_ + h)*64 + ni*16 + lr] =
            __float2bfloat16(acc[mi][ni][i] * inv);
    }
  }
}

// ---------------- head (bf16 h) --------------------------------------------
__global__ __launch_bounds__(256)
void head_k(const bf16* __restrict__ h, const float* __restrict__ fcw,
            const float* __restrict__ fcb, float* __restrict__ out)
{
  __shared__ float red[256][2];
  const int b = blockIdx.x, tid = threadIdx.x;
  const bf16* hb = h + (size_t)b*S_*D_;
  float s0=0.f, s1=0.f;
  for (int s=0; s<S_; ++s){
    s0 += bf2f(*(const unsigned short*)&hb[(size_t)s*D_ + tid]);
    s1 += bf2f(*(const unsigned short*)&hb[(size_t)s*D_ + tid + 256]);
  }
  const float m0 = s0*(1.f/S_), m1 = s1*(1.f/S_);
  red[tid][0] = m0*fcw[tid*2+0] + m1*fcw[(tid+256)*2+0];
  red[tid][1] = m0*fcw[tid*2+1] + m1*fcw[(tid+256)*2+1];
  __syncthreads();
  for (int st=128; st; st>>=1){
    if (tid<st){ red[tid][0]+=red[tid+st][0]; red[tid][1]+=red[tid+st][1]; }
    __syncthreads();
  }
  if (tid==0){ out[b*2+0]=red[0][0]+fcb[0]; out[b*2+1]=red[0][1]+fcb[1]; }
}

extern "C" void kernel_launch(void* const* d_in, const int* in_sizes, int n_in,
                              void* d_out, int out_size, void* d_ws, size_t ws_size,
                              hipStream_t stream)
{
  const float* x     = (const float*)d_in[0];
  const float* emb_w = (const float*)d_in[1];
  const float* emb_b = (const float*)d_in[2];
  const float* pos   = (const float*)d_in[3];
  const float* ln1_g = (const float*)d_in[4];
  const float* ln1_b = (const float*)d_in[5];
  const float* wq    = (const float*)d_in[6];
  const float* bq    = (const float*)d_in[7];
  const float* wk    = (const float*)d_in[8];
  const float* bk    = (const float*)d_in[9];
  const float* wv    = (const float*)d_in[10];
  const float* bv    = (const float*)d_in[11];
  const float* wo    = (const float*)d_in[12];
  const float* bo    = (const float*)d_in[13];
  const float* proj  = (const float*)d_in[14];
  const float* ln2_g = (const float*)d_in[15];
  const float* ln2_b = (const float*)d_in[16];
  const float* w1    = (const float*)d_in[17];
  const float* b1    = (const float*)d_in[18];
  const float* w2    = (const float*)d_in[19];
  const float* b2    = (const float*)d_in[20];
  const float* fc_w  = (const float*)d_in[21];
  const float* fc_b  = (const float*)d_in[22];
  float* out = (float*)d_out;

  const size_t W55 = (size_t)512*512, W52 = (size_t)512*2048;
  const size_t WCAT = (size_t)1536*512;

  char* p = (char*)d_ws;
  auto take = [&](size_t bytes)->char*{
    char* r = p; p += (bytes + 255) & ~(size_t)255; return r;
  };
  bf16* Wcat = (bf16*)take(L_*WCAT*2);
  bf16* woT  = (bf16*)take(L_*W55*2);
  bf16* w1T  = (bf16*)take(L_*W52*2);
  bf16* w2T  = (bf16*)take(L_*W52*2);
  bf16* embT = (bf16*)take((size_t)64*512*2);
  bf16* xbf  = (bf16*)take((size_t)B_*S_*DIN_*2);
  bf16* posbf= (bf16*)take((size_t)S_*512*2);
  float* bcat= (float*)take(L_*1536*4);
  float* invm= (float*)take(L_*64*4);
  const size_t fixed_bytes = (size_t)(p - (char*)d_ws);

  // NB=32, full-row FFN hidden (round-15 best config).
  int NB = 32; size_t need = 0;
  for (;; NB >>= 1){
    size_t RC = (size_t)NB*S_, nbh = (size_t)NB*H_;
    need = fixed_bytes + RC*(5*1024 + 4096) + nbh*(8192+256) + 65536;
    if (need <= ws_size || NB == 1) break;
  }
  if (need > ws_size) return;
  const size_t RC = (size_t)NB*S_;
  const int NBH = NB*H_, rows = (int)RC;

  bf16*  hbuf = (bf16*)take(RC*512*2);    // residual stream bf16
  bf16*  qpb  = (bf16*)take(RC*512*2);    // qp
  bf16*  ddk  = (bf16*)take(RC*512*2);    // ddk' (bf16)
  bf16*  vbf  = (bf16*)take(RC*512*2);    // v
  bf16*  ybf  = (bf16*)take(RC*512*2);
  bf16*  hidbf= (bf16*)take(RC*2048*2);   // FFN hidden (full-row)
  bf16*  ctxT = (bf16*)take((size_t)NBH*4096*2);
  float* kps  = (float*)take((size_t)NBH*64*4);

  dim3 blk(256), blk5(512);

  // ---- per-launch weight prep ----
  for (int l=0; l<L_; ++l){
    bf16* Wl = Wcat + (size_t)l*WCAT;
    float* bl = bcat + (size_t)l*1536;
    projw_k<<<dim3(8,8),   blk, 0, stream>>>(wq + l*W55, proj + l*4096, Wl, 0);
    projw_k<<<dim3(8,8),   blk, 0, stream>>>(wk + l*W55, proj + l*4096, Wl, 512);
    convT_k<<<dim3(16,16), blk, 0, stream>>>(wv + l*W55, Wl, 512, 512, 1024, 64);
    bpack_k<<<6, blk, 0, stream>>>(bq + l*512, bk + l*512, bv + l*512, proj + l*4096, bl);
    invm_k<<<1, 64, 0, stream>>>(proj + l*4096, invm + l*64);
    convT_k<<<dim3(16,16), blk, 0, stream>>>(wo + l*W55, woT + l*W55, 512, 512, 0, 64);
    convT_k<<<dim3(64,16), blk, 0, stream>>>(w1 + l*W52, w1T + l*W52, 512, 2048, 0, 64);
    convT_k<<<dim3(16,64), blk, 0, stream>>>(w2 + l*W52, w2T + l*W52, 2048, 512, 0, 64);
  }
  convT_k<<<dim3(16,2), blk, 0, stream>>>(emb_w, embT, 64, 512, 0, 64);
  conv_k<<<(B_*S_*DIN_/4 + 255)/256, blk, 0, stream>>>(x, xbf, B_*S_*DIN_/4);
  conv_k<<<(S_*512/4 + 255)/256, blk, 0, stream>>>(pos, posbf, S_*512/4);

  const int rg128 = (rows + 127)/128;
  const int rg256 = (rows + 255)/256;

  for (int bc = 0; bc < B_/NB; ++bc){
    const bf16* xc = xbf + (size_t)bc*RC*DIN_;
    float* outc = out + (size_t)bc*NB*2;

    gemm2_k<0,1,1><<<4*rg128, blk, 0, stream>>>(
        xc, embT, emb_b, posbf, nullptr, hbuf, rows, 512, 64, S_, 4);

    for (int l=0; l<L_; ++l){
      ln_k<<<2048, blk, 0, stream>>>(hbuf, ln1_g + l*512, ln1_b + l*512, ybf, rows);
      mega256_k<<<6*rg256, blk5, 0, stream>>>(
          ybf, Wcat + (size_t)l*WCAT, bcat + (size_t)l*1536, invm + l*64, rows,
          qpb, ddk, vbf, 6);
      fctx_k<<<NBH, blk, 0, stream>>>(ddk, vbf, ctxT, kps);
      attnmm_k<<<dim3(NBH, (S_+255)/256), blk, 0, stream>>>(qpb, ctxT, kps, ybf);
      gemm256_k<0,1,1><<<2*rg256, blk5, 0, stream>>>(
          ybf, woT + l*W55, bo + l*512, hbuf, nullptr, hbuf, rows, 512, 512, 2);
      ln_k<<<2048, blk, 0, stream>>>(hbuf, ln2_g + l*512, ln2_b + l*512, ybf, rows);
      gemm256_k<1,0,1><<<8*rg256, blk5, 0, stream>>>(
          ybf, w1T + l*W52, b1 + l*2048, nullptr, nullptr, hidbf, rows, 2048, 512, 8);
      gemm256_k<0,1,1><<<2*rg256, blk5, 0, stream>>>(
          hidbf, w2T + l*W52, b2 + l*512, hbuf, nullptr, hbuf, rows, 512, 2048, 2);
    }
    head_k<<<NB, blk, 0, stream>>>(hbuf, fc_w, fc_b, outc);
  }
}